// Round 14
// baseline (745.352 us; speedup 1.0000x reference)
//
#include <hip/hip_runtime.h>
#include <hip/hip_bf16.h>

// DGCNN_Seg forward. B=2, N=4096, K=20. fp32 in/out.
// Round 29: R28 base (622us ~ R26's 613 within noise; k_dist 64x64 @80us
// clean counters) + fused pass-1 kNN. C=3 keys cost 6 VALU each -> stream
// them on the fly (R21-verified fmaf chain) + rank-by-count selection
// (R26-verified, ~9 crossbar ops): kills pass-1 k_dist(80)+k_topk16(37),
// replaced by one ~30us kernel. Phase A: lane-min -> LDS u64 rank ->
// exact 20th-lane-min threshold (superset bound, exact keys). Phase B:
// re-stream predicate -> compact -> u64 rank -> write (key,j)-ascending.
// Fallback >64 cands: threshold-walk pop (never runs). Passes 2-4 unchanged.

#define DEVI static __device__ __forceinline__
typedef __attribute__((ext_vector_type(8))) short bf16x8;   // 8 bf16 = 4 VGPR
typedef __attribute__((ext_vector_type(4))) float f32x4;    // MFMA acc
typedef unsigned long long ull;

DEVI float lrelu(float y) { return y > 0.f ? y : 0.2f * y; }
DEVI unsigned okey(float f) {
  unsigned u = __float_as_uint(f);
  return (f < 0.f) ? ~u : (u | 0x80000000u);
}
DEVI float dekey(unsigned k) {
  return __uint_as_float((k & 0x80000000u) ? (k & 0x7fffffffu) : ~k);
}

// ---------------- weight fp32 -> bf16 pack ----------------
__global__ __launch_bounds__(64) void k_conv(const float* __restrict__ src, int lds, int off,
                                             int sub, int Kc, __hip_bfloat16* __restrict__ dst) {
  int o = blockIdx.x, c = blockIdx.y * 64 + threadIdx.x;
  float v = src[(size_t)o * lds + off + c];
  if (sub) v -= src[(size_t)o * lds + c];
  dst[(size_t)o * Kc + c] = __float2bfloat16(v);
}

// ---------------- row squared-norms: one wave per row ----------------
__global__ __launch_bounds__(256) void k_xx(const float* __restrict__ F, int ldf, int C,
                                            float* __restrict__ xx) {
  int lane = threadIdx.x & 63;
  int row = blockIdx.x * 4 + (threadIdx.x >> 6);
  const float* f = F + (size_t)row * ldf;
  float s = 0.f;
  for (int c = lane; c < C; c += 64) { float v = f[c]; s += v * v; }
#pragma unroll
  for (int off = 32; off; off >>= 1) s += __shfl_xor(s, off, 64);
  if (lane == 0) xx[row] = s;
}

// ---------------- fused kNN pass 1 (C=3): one wave/row, rank-by-count ----------------
// Keys streamed on the fly (R21-verified fmaf chain), never stored.
// Phase A: lane-min (key,t) -> LDS u64 rank-by-count -> (hk,hj) = 20th
// smallest lane-min pair (superset bound: exact top-20 all <=lex (hk,hj)).
// Phase B: re-stream predicate -> prefix-compact (key,j) pairs to LDS ->
// u64 rank-by-count -> lanes write op[rank], ascending (key,j) == jax.
__global__ __launch_bounds__(256) void k_knn3(const float* __restrict__ xf,
                                              const float* __restrict__ xx,
                                              int* __restrict__ idx) {
  __shared__ ull LP[4][64];   // phase-A lane-min packs
  __shared__ ull LQ[4][64];   // candidate (key<<32|j) pairs
  const int tid = threadIdx.x, lane = tid & 63, wv = tid >> 6;
  const int row = blockIdx.x * 4 + wv;  // 0..8191
  const int b = row >> 12, i = row & 4095;
  const float* xb = xf + (size_t)(b << 12) * 3;
  const float* xxb = xx + (b << 12);
  const float xi0 = xb[(size_t)i * 3], xi1 = xb[(size_t)i * 3 + 1], xi2 = xb[(size_t)i * 3 + 2];
  const float xxi = xxb[i];
  const float* pj = xb + (size_t)lane * 64 * 3;
  const float* xxj = xxb + lane * 64;
  int* op = idx + (size_t)row * 20;
  auto key1 = [&](int t) {
    const float y0 = pj[t * 3], y1 = pj[t * 3 + 1], y2 = pj[t * 3 + 2];
    // R21-verified chain: dot = fmaf(xi2,y2, fmaf(xi1,y1, xi0*y0))
    const float dot = fmaf(xi2, y2, fmaf(xi1, y1, xi0 * y0));
    return okey(xxi + xxj[t] - 2.f * dot);
  };
  // ---- phase A: lane-min (strict < keeps smallest t -> smallest j) ----
  unsigned mk = 0xFFFFFFFFu;
  int mp = 0;
#pragma unroll 8
  for (int t = 0; t < 64; ++t) {
    unsigned k = key1(t);
    if (k < mk) { mk = k; mp = t; }
  }
  const ull mine = ((ull)mk << 32) | (unsigned)(lane * 64 + mp);
  LP[wv][lane] = mine;
  asm volatile("s_waitcnt lgkmcnt(0)" ::: "memory");
  __builtin_amdgcn_sched_barrier(0);
  int rank = 0;
#pragma unroll
  for (int t = 0; t < 64; ++t) rank += (LP[wv][t] < mine) ? 1 : 0;
  const ull bal = __ballot(rank == 19);
  const int sl = (int)(__ffsll((unsigned long long)bal) - 1);
  const unsigned hk = __shfl((unsigned)(mine >> 32), sl, 64);
  const unsigned hj = __shfl((unsigned)(mine & 0xFFFFFFFFu), sl, 64);
  // ---- phase B: predicate re-stream + count ----
  ull pmask = 0;
  int cnt = 0;
#pragma unroll 8
  for (int t = 0; t < 64; ++t) {
    unsigned k = key1(t);
    unsigned j = (unsigned)(lane * 64 + t);
    if (k < hk || (k == hk && j <= hj)) { pmask |= 1ull << t; ++cnt; }
  }
  int inc = cnt;
#pragma unroll
  for (int off = 1; off < 64; off <<= 1) {
    int v = __shfl_up(inc, off, 64);
    if (lane >= off) inc += v;
  }
  const int total = __shfl(inc, 63, 64);
  if (total <= 64) {
    LQ[wv][lane] = 0xFFFFFFFFFFFFFFFFull;
    asm volatile("s_waitcnt lgkmcnt(0)" ::: "memory");
    __builtin_amdgcn_sched_barrier(0);
    int s = inc - cnt;
    while (pmask) {
      int t = (int)(__ffsll(pmask) - 1);
      pmask &= pmask - 1;
      LQ[wv][s++] = ((ull)key1(t) << 32) | (unsigned)(lane * 64 + t);
    }
    asm volatile("s_waitcnt lgkmcnt(0)" ::: "memory");
    __builtin_amdgcn_sched_barrier(0);
    const ull me = LQ[wv][lane];
    int r2 = 0;
#pragma unroll
    for (int t = 0; t < 64; ++t) r2 += (LQ[wv][t] < me) ? 1 : 0;
    if (lane < total && r2 < 20) op[r2] = (int)(me & 4095u);
    return;
  }
  // ---- fallback (massive ties; never runs): threshold-walk pop min ----
  ull last = 0;
  for (int r = 0; r < 20; ++r) {
    ull best = 0xFFFFFFFFFFFFFFFFull;
    for (int t = 0; t < 64; ++t) {
      ull p = ((ull)key1(t) << 32) | (unsigned)(lane * 64 + t);
      if (p > last && p < best) best = p;
    }
    unsigned bh = (unsigned)(best >> 32), bl = (unsigned)best;
#pragma unroll
    for (int off = 32; off; off >>= 1) {
      unsigned qh = __shfl_xor(bh, off, 64);
      unsigned ql = __shfl_xor(bl, off, 64);
      if (qh < bh || (qh == bh && ql < bl)) { bh = qh; bl = ql; }
    }
    if (lane == 0) op[r] = (int)(bl & 4095u);
    last = ((ull)bh << 32) | bl;
  }
}

// ---------------- pairwise distances: 64(i)x64(j) tile, 4x4 acc, u16 keys ----------------
// Triangular bj>=bi (2080 tiles/batch); diagonal tiles cover both triangles,
// off-diagonal mirror from registers. Stores okey(d)>>16 (u16). fmaf order
// ascending c (zero-padded tail exact) -> k_topk16 recompute bit-identical.
__global__ __launch_bounds__(256) void k_dist(const float* __restrict__ F, int ldf, int C,
                                              const float* __restrict__ xx,
                                              unsigned short* __restrict__ D) {
  __shared__ __align__(16) float As[16][68];
  __shared__ __align__(16) float Bs[16][68];
  const int tid = threadIdx.x;
  const int tx = tid & 15, ty = tid >> 4;
  int bi, bj;
  {
    int t = blockIdx.x;
    bi = 0;
    while (t >= 64 - bi) { t -= 64 - bi; ++bi; }
    bj = bi + t;
  }
  const int b = blockIdx.z;
  unsigned short* Db = D + (size_t)b * 4096 * 4096;
  const int i0 = bi * 64, j0 = bj * 64;
  const float* Fb = F + (size_t)b * 4096 * ldf;
  const float* xxb = xx + b * 4096;
  const int row = tid >> 2, q = (tid & 3) * 4;  // stage: 64 rows x 16 cols
  float acc[4][4] = {};
  for (int c0 = 0; c0 < C; c0 += 16) {
    if (C - c0 >= 16) {
      float4 a = *(const float4*)(Fb + (size_t)(i0 + row) * ldf + c0 + q);
      As[q + 0][row] = a.x; As[q + 1][row] = a.y; As[q + 2][row] = a.z; As[q + 3][row] = a.w;
      float4 w = *(const float4*)(Fb + (size_t)(j0 + row) * ldf + c0 + q);
      Bs[q + 0][row] = w.x; Bs[q + 1][row] = w.y; Bs[q + 2][row] = w.z; Bs[q + 3][row] = w.w;
    } else {
#pragma unroll
      for (int e = 0; e < 4; ++e) {
        int c = c0 + q + e;
        As[q + e][row] = (c < C) ? Fb[(size_t)(i0 + row) * ldf + c] : 0.f;
        Bs[q + e][row] = (c < C) ? Fb[(size_t)(j0 + row) * ldf + c] : 0.f;
      }
    }
    __syncthreads();
#pragma unroll
    for (int kk = 0; kk < 16; ++kk) {
      const float4 a4 = *(const float4*)&As[kk][ty * 4];
      const float4 b4 = *(const float4*)&Bs[kk][tx * 4];
      const float av[4] = {a4.x, a4.y, a4.z, a4.w};
      const float bv[4] = {b4.x, b4.y, b4.z, b4.w};
#pragma unroll
      for (int ii = 0; ii < 4; ++ii)
#pragma unroll
        for (int jj = 0; jj < 4; ++jj)
          acc[ii][jj] = fmaf(av[ii], bv[jj], acc[ii][jj]);
    }
    __syncthreads();
  }
  // normal store: rows i0+ty*4+ii, cols j0+tx*4.. (uint2 = 4 u16)
#pragma unroll
  for (int ii = 0; ii < 4; ++ii) {
    const int i = i0 + ty * 4 + ii;
    const float xi = xxb[i];
    unsigned k0 = okey(xi + xxb[j0 + tx * 4 + 0] - 2.f * acc[ii][0]) >> 16;
    unsigned k1 = okey(xi + xxb[j0 + tx * 4 + 1] - 2.f * acc[ii][1]) >> 16;
    unsigned k2 = okey(xi + xxb[j0 + tx * 4 + 2] - 2.f * acc[ii][2]) >> 16;
    unsigned k3 = okey(xi + xxb[j0 + tx * 4 + 3] - 2.f * acc[ii][3]) >> 16;
    uint2 o;
    o.x = (k1 << 16) | k0;
    o.y = (k3 << 16) | k2;
    *(uint2*)&Db[(size_t)i * 4096 + j0 + tx * 4] = o;
  }
  // mirror store (strictly off-diagonal tiles): transpose block
  if (bj > bi) {
#pragma unroll
    for (int jj = 0; jj < 4; ++jj) {
      const int j = j0 + tx * 4 + jj;
      const float xj = xxb[j];
      unsigned h0 = okey(xxb[i0 + ty * 4 + 0] + xj - 2.f * acc[0][jj]) >> 16;
      unsigned h1 = okey(xxb[i0 + ty * 4 + 1] + xj - 2.f * acc[1][jj]) >> 16;
      unsigned h2 = okey(xxb[i0 + ty * 4 + 2] + xj - 2.f * acc[2][jj]) >> 16;
      unsigned h3 = okey(xxb[i0 + ty * 4 + 3] + xj - 2.f * acc[3][jj]) >> 16;
      uint2 m;
      m.x = (h1 << 16) | h0;
      m.y = (h3 << 16) | h2;
      *(uint2*)&Db[(size_t)j * 4096 + i0 + ty * 4] = m;
    }
  }
}

// ---------------- top-20 v3: rank-by-count, minimal cross-lane ----------------
__global__ __launch_bounds__(256) void k_topk16(const unsigned short* __restrict__ Dk,
                                                const float* __restrict__ F, int ldf, int C,
                                                const float* __restrict__ xx,
                                                int* __restrict__ idx) {
  __shared__ unsigned LM[4][64];   // lane-min packs
  __shared__ unsigned LC[4][64];   // candidate j list
  __shared__ ull LPair[4][64];     // (ekey<<32)|j pairs
  const int tid = threadIdx.x, lane = tid & 63, wv = tid >> 6;
  const int ir = blockIdx.x * 4 + wv;   // 0..4095
  const int b = blockIdx.y;
  const unsigned short* drow = Dk + (size_t)b * 4096 * 4096 + (size_t)ir * 4096;
  const float* Fb = F + (size_t)b * 4096 * ldf;
  const float* xxb = xx + (size_t)b * 4096;
  int* op = idx + ((size_t)b * 4096 + ir) * 20;
  // load row: 8 x uint4 (8 u16 keys each), j = q*512 + lane*8 + e
  uint4 kw[8];
  {
    const uint4* dp = (const uint4*)drow;
#pragma unroll
    for (int q = 0; q < 8; ++q) kw[q] = dp[q * 64 + lane];
  }
  // pin in VGPRs (R25: compiler rematerialized -> 2x global reads)
#pragma unroll
  for (int q = 0; q < 8; ++q)
    asm volatile("" : "+v"(kw[q].x), "+v"(kw[q].y), "+v"(kw[q].z), "+v"(kw[q].w));
  // ---- phase A: lane-min of packs (k16<<12 | j) ----
  unsigned smin = 0xFFFFFFFFu;
#pragma unroll
  for (int q = 0; q < 8; ++q) {
    const unsigned jb = (unsigned)(q * 512 + lane * 8);
    const unsigned w[4] = {kw[q].x, kw[q].y, kw[q].z, kw[q].w};
#pragma unroll
    for (int h = 0; h < 4; ++h) {
      const unsigned p0 = ((w[h] & 0xFFFFu) << 12) | (jb + 2 * h);
      const unsigned p1 = ((w[h] >> 16) << 12) | (jb + 2 * h + 1);
      smin = p0 < smin ? p0 : smin;
      smin = p1 < smin ? p1 : smin;
    }
  }
  // rank-by-count over 64 lane-mins (LDS broadcast reads, no crossbar)
  LM[wv][lane] = smin;
  asm volatile("s_waitcnt lgkmcnt(0)" ::: "memory");
  __builtin_amdgcn_sched_barrier(0);
  int rank = 0;
#pragma unroll
  for (int t = 0; t < 64; ++t) rank += (LM[wv][t] < smin) ? 1 : 0;
  const ull bal = __ballot(rank == 19);
  const int sl = (int)(__ffsll((unsigned long long)bal) - 1);
  const unsigned t16 = __shfl(smin, sl, 64) >> 12;
  // ---- phase B: candidate mask (k16 <= t16) from regs ----
  ull pmask = 0;
  int cnt = 0;
#pragma unroll
  for (int q = 0; q < 8; ++q) {
    const unsigned w[4] = {kw[q].x, kw[q].y, kw[q].z, kw[q].w};
#pragma unroll
    for (int h = 0; h < 4; ++h) {
      if ((w[h] & 0xFFFFu) <= t16) { pmask |= 1ull << (q * 8 + 2 * h);     ++cnt; }
      if ((w[h] >> 16)     <= t16) { pmask |= 1ull << (q * 8 + 2 * h + 1); ++cnt; }
    }
  }
  int inc = cnt;
#pragma unroll
  for (int off = 1; off < 64; off <<= 1) {
    int v = __shfl_up(inc, off, 64);
    if (lane >= off) inc += v;
  }
  const int total = __shfl(inc, 63, 64);
  if (total <= 64) {
    int s = inc - cnt;
    while (pmask) {
      int t = (int)(__ffsll(pmask) - 1);
      pmask &= pmask - 1;
      LC[wv][s++] = (unsigned)((t >> 3) * 512 + lane * 8 + (t & 7));
    }
    asm volatile("s_waitcnt lgkmcnt(0)" ::: "memory");
    __builtin_amdgcn_sched_barrier(0);
    unsigned cp = (lane < total) ? LC[wv][lane] : 0xFFFFFFFFu;
    asm volatile("s_waitcnt lgkmcnt(0)" ::: "memory");
    unsigned ekey = 0xFFFFFFFFu;
    if (lane < total) {
      const float* xip = Fb + (size_t)ir * ldf;
      const float* xjp = Fb + (size_t)cp * ldf;
      float dot = 0.f;
      int c = 0;
      for (; c + 4 <= C; c += 4) {   // same chain order as k_dist (ascending c)
        const float4 a = *(const float4*)(xip + c);
        const float4 g = *(const float4*)(xjp + c);
        dot = fmaf(a.x, g.x, dot);
        dot = fmaf(a.y, g.y, dot);
        dot = fmaf(a.z, g.z, dot);
        dot = fmaf(a.w, g.w, dot);
      }
      for (; c < C; ++c) dot = fmaf(xip[c], xjp[c], dot);
      ekey = okey(xxb[ir] + xxb[cp] - 2.f * dot);
    }
    // final rank-by-count on (ekey, j) u64 pairs (LDS broadcast)
    const ull me = ((ull)ekey << 32) | cp;
    LPair[wv][lane] = me;
    asm volatile("s_waitcnt lgkmcnt(0)" ::: "memory");
    __builtin_amdgcn_sched_barrier(0);
    int r2 = 0;
#pragma unroll
    for (int t = 0; t < 64; ++t) r2 += (LPair[wv][t] < me) ? 1 : 0;
    if (lane < total && r2 < 20) op[r2] = (int)cp;
    return;
  }
  // ---- fallback (massive u16 ties; correct, effectively never runs) ----
  ull consumed = 0;
  for (int r = 0; r < 20; ++r) {
    unsigned bk = 0xFFFFFFFFu, bp = 0xFFFFu;
    for (int t = 0; t < 64; ++t) {
      if ((consumed >> t) & 1ull) continue;
      unsigned p = (unsigned)(t * 64 + lane);
      const float* xip = Fb + (size_t)ir * ldf;
      const float* xjp = Fb + (size_t)p * ldf;
      float dot = 0.f;
      for (int c = 0; c < C; ++c) dot = fmaf(xip[c], xjp[c], dot);
      unsigned ek = okey(xxb[ir] + xxb[p] - 2.f * dot);
      if (ek < bk || (ek == bk && p < bp)) { bk = ek; bp = p; }
    }
    unsigned mk = bk, mp = bp;
#pragma unroll
    for (int off = 32; off; off >>= 1) {
      unsigned ok2 = __shfl_xor(mk, off, 64);
      unsigned op2 = __shfl_xor(mp, off, 64);
      if (ok2 < mk || (ok2 == mk && op2 < mp)) { mk = ok2; mp = op2; }
    }
    if (lane == 0) op[r] = (int)mp;
    if (bk == mk && bp == mp) consumed |= 1ull << (mp >> 6);
  }
}

// ---------------- EdgeConv layer 1 (fp32, Cin=3): one wave per point ----------------
__global__ __launch_bounds__(256) void k_edge1(const float* __restrict__ xf,
                                               const float* __restrict__ W1,
                                               const float* __restrict__ s1,
                                               const float* __restrict__ b1,
                                               const int* __restrict__ idx,
                                               float* __restrict__ xcat,
                                               __hip_bfloat16* __restrict__ xcatb) {
  const int lane = threadIdx.x & 63;
  const int p = blockIdx.x * 4 + (threadIdx.x >> 6);
  const int bb = p >> 12;
  float wl[3], wr[3];
#pragma unroll
  for (int c = 0; c < 3; ++c) {
    wl[c] = W1[lane * 6 + c];
    wr[c] = W1[lane * 6 + 3 + c];
  }
  const float s = s1[lane], bi = b1[lane];
  const float* xc = xf + (size_t)p * 3;
  const float x0 = xc[0], x1 = xc[1], x2 = xc[2];
  const float t = x0 * (wr[0] - wl[0]) + x1 * (wr[1] - wl[1]) + x2 * (wr[2] - wl[2]);
  const int* ir = idx + (size_t)p * 20;
  float best = -INFINITY;
  for (int k = 0; k < 20; ++k) {
    int j = ir[k];
    const float* xn = xf + ((size_t)(bb << 12) + j) * 3;
    float y = t + xn[0] * wl[0] + xn[1] * wl[1] + xn[2] * wl[2];
    y = lrelu(y * s + bi);
    best = fmaxf(best, y);
  }
  xcat[(size_t)p * 512 + lane] = best;
  xcatb[(size_t)p * 512 + lane] = __float2bfloat16(best);
}

// ---------------- fp32 pointwise GEMM, raw store (T for layers 2-3) ----------------
__global__ __launch_bounds__(256) void k_pwT(const float* __restrict__ A, int lda, int K,
                                             const float* __restrict__ W, int ldw, int wsub,
                                             float* __restrict__ out, int ldo) {
  __shared__ __align__(16) float As[16][68];
  __shared__ __align__(16) float Bs[16][68];
  const int tid = threadIdx.x;
  const int tx = tid & 15, ty = tid >> 4;
  const int i0 = blockIdx.x * 64, o0 = blockIdx.y * 64;
  const int row = tid >> 2, q = (tid & 3) * 4;
  float acc[4][4] = {};
  for (int c0 = 0; c0 < K; c0 += 16) {
    float4 a = *(const float4*)(A + (size_t)(i0 + row) * lda + c0 + q);
    As[q + 0][row] = a.x; As[q + 1][row] = a.y; As[q + 2][row] = a.z; As[q + 3][row] = a.w;
    const float* wp = W + (size_t)(o0 + row) * ldw + c0 + q;
#pragma unroll
    for (int e = 0; e < 4; ++e) Bs[q + e][row] = wp[wsub + e] - wp[e];
    __syncthreads();
#pragma unroll
    for (int kk = 0; kk < 16; ++kk) {
      const float4 a4 = *(const float4*)&As[kk][ty * 4];
      const float4 b4 = *(const float4*)&Bs[kk][tx * 4];
      const float av[4] = {a4.x, a4.y, a4.z, a4.w};
      const float bv[4] = {b4.x, b4.y, b4.z, b4.w};
#pragma unroll
      for (int ii = 0; ii < 4; ++ii)
#pragma unroll
        for (int jj = 0; jj < 4; ++jj)
          acc[ii][jj] = fmaf(av[ii], bv[jj], acc[ii][jj]);
    }
    __syncthreads();
  }
#pragma unroll
  for (int ii = 0; ii < 4; ++ii)
#pragma unroll
    for (int jj = 0; jj < 4; ++jj)
      out[(size_t)(i0 + ty * 4 + ii) * ldo + o0 + tx * 4 + jj] = acc[ii][jj];
}

// ---------------- fp32 EdgeConv GEMM (layers 2-3; feeds kNN, stays exact) ----------------
__global__ __launch_bounds__(256) void k_edge(const float* __restrict__ F, int ldf, int Cin,
                                              const float* __restrict__ W,
                                              const float* __restrict__ sc,
                                              const float* __restrict__ bi,
                                              const int* __restrict__ idx,
                                              const float* __restrict__ T, int ldt,
                                              float* __restrict__ out,
                                              __hip_bfloat16* __restrict__ outb) {
  __shared__ float As[16][81];
  __shared__ __align__(16) float Bs[16][68];
  __shared__ float Ys[80][65];
  const int tid = threadIdx.x;
  const int tx = tid & 15, ty = tid >> 4;
  const int r0 = blockIdx.x * 80;
  const int o0 = blockIdx.y * 64;
  const int ldw = 2 * Cin;
  int grow[5], gcol[5];
#pragma unroll
  for (int l = 0; l < 5; ++l) {
    int e = tid + l * 256;
    int rr = e >> 4;
    gcol[l] = e & 15;
    int gr = r0 + rr;
    int p = gr / 20;
    int j = idx[(size_t)p * 20 + (gr % 20)];
    grow[l] = ((p >> 12) << 12) + j;
  }
  float acc[5][4] = {};
  const int wrow = tid >> 2, wq = (tid & 3) * 4;
  for (int c0 = 0; c0 < Cin; c0 += 16) {
#pragma unroll
    for (int l = 0; l < 5; ++l) {
      int e = tid + l * 256;
      As[gcol[l]][e >> 4] = F[(size_t)grow[l] * ldf + c0 + gcol[l]];
    }
    {
      const float* wp = W + (size_t)(o0 + wrow) * ldw + c0 + wq;
#pragma unroll
      for (int e = 0; e < 4; ++e) Bs[wq + e][wrow] = wp[e];
    }
    __syncthreads();
#pragma unroll
    for (int kk = 0; kk < 16; ++kk) {
      float a[5];
#pragma unroll
      for (int l = 0; l < 5; ++l) a[l] = As[kk][ty + l * 16];
      const float4 b4 = *(const float4*)&Bs[kk][tx * 4];
      const float bv[4] = {b4.x, b4.y, b4.z, b4.w};
#pragma unroll
      for (int l = 0; l < 5; ++l)
#pragma unroll
        for (int jj = 0; jj < 4; ++jj)
          acc[l][jj] = fmaf(a[l], bv[jj], acc[l][jj]);
    }
    __syncthreads();
  }
#pragma unroll
  for (int l = 0; l < 5; ++l) {
    int r = ty + l * 16;
    int p = (r0 + r) / 20;
#pragma unroll
    for (int jj = 0; jj < 4; ++jj) {
      int o = o0 + tx * 4 + jj;
      float y = (acc[l][jj] + T[(size_t)p * ldt + o]) * sc[o] + bi[o];
      Ys[r][tx * 4 + jj] = lrelu(y);
    }
  }
  __syncthreads();
  const int grp = tid >> 6, col = tid & 63;
  float m = -INFINITY;
#pragma unroll
  for (int k = 0; k < 20; ++k) m = fmaxf(m, Ys[grp * 20 + k][col]);
  const int p = blockIdx.x * 4 + grp;
  out[(size_t)p * 512 + o0 + col] = m;
  outb[(size_t)p * 512 + o0 + col] = __float2bfloat16(m);
}

// ---------------- MFMA bf16 GEMM: block 128(M)x64(N), 4 waves x (32x64) ----------------
template <int EPI>
__global__ __launch_bounds__(256) void k_mm(
    const __hip_bfloat16* __restrict__ A, int lda, int K,
    const __hip_bfloat16* __restrict__ B,  // [N][K] bf16
    const float* __restrict__ sc, const float* __restrict__ bi,
    const float* __restrict__ extra, int Ncols,
    float* __restrict__ outf, int ldof,
    __hip_bfloat16* __restrict__ outb, int ldob,
    unsigned* __restrict__ gmax) {
  __shared__ __align__(16) __hip_bfloat16 Al[128 * 40];
  __shared__ __align__(16) __hip_bfloat16 Bl[64 * 40];
  __shared__ float Red[4][64];
  const int tid = threadIdx.x, lane = tid & 63, wv = tid >> 6;
  const int m0 = blockIdx.x * 128, n0 = blockIdx.y * 64;
  const int arow = tid >> 2, akc = (tid & 3) * 8;
  const int fm = lane & 15, fq = lane >> 4;
  f32x4 acc[2][4];
#pragma unroll
  for (int mt = 0; mt < 2; ++mt)
#pragma unroll
    for (int nt = 0; nt < 4; ++nt) acc[mt][nt] = (f32x4){0.f, 0.f, 0.f, 0.f};
  for (int c0 = 0; c0 < K; c0 += 32) {
#pragma unroll
    for (int l = 0; l < 2; ++l) {
      int r = arow + l * 64;
      *(float4*)&Al[r * 40 + akc] = *(const float4*)(A + (size_t)(m0 + r) * lda + c0 + akc);
    }
    *(float4*)&Bl[arow * 40 + akc] = *(const float4*)(B + (size_t)(n0 + arow) * K + c0 + akc);
    __syncthreads();
    bf16x8 af[2], bfr[4];
#pragma unroll
    for (int mt = 0; mt < 2; ++mt)
      af[mt] = *(const bf16x8*)&Al[(wv * 32 + mt * 16 + fm) * 40 + fq * 8];
#pragma unroll
    for (int nt = 0; nt < 4; ++nt)
      bfr[nt] = *(const bf16x8*)&Bl[(nt * 16 + fm) * 40 + fq * 8];
#pragma unroll
    for (int mt = 0; mt < 2; ++mt)
#pragma unroll
      for (int nt = 0; nt < 4; ++nt)
        acc[mt][nt] = __builtin_amdgcn_mfma_f32_16x16x32_bf16(af[mt], bfr[nt], acc[mt][nt], 0, 0, 0);
    __syncthreads();
  }
  const int bidx = m0 >> 12;
  if (EPI == 0) {
#pragma unroll
    for (int mt = 0; mt < 2; ++mt)
#pragma unroll
      for (int nt = 0; nt < 4; ++nt)
#pragma unroll
        for (int r = 0; r < 4; ++r)
          outf[(size_t)(m0 + wv * 32 + mt * 16 + fq * 4 + r) * ldof + n0 + nt * 16 + fm] =
              acc[mt][nt][r];
  } else if (EPI == 1) {
#pragma unroll
    for (int nt = 0; nt < 4; ++nt) {
      int col = n0 + nt * 16 + fm;
      float s = sc[col], bb = bi[col];
      float ex = extra ? extra[bidx * Ncols + col] : 0.f;
#pragma unroll
      for (int mt = 0; mt < 2; ++mt)
#pragma unroll
        for (int r = 0; r < 4; ++r) {
          float v = lrelu((acc[mt][nt][r] + ex) * s + bb);
          size_t rr = (size_t)(m0 + wv * 32 + mt * 16 + fq * 4 + r);
          if (outf) outf[rr * ldof + col] = v;
          if (outb) outb[rr * ldob + col] = __float2bfloat16(v);
        }
    }
  } else {
#pragma unroll
    for (int nt = 0; nt < 4; ++nt) {
      int col = n0 + nt * 16 + fm;
      float s = sc[col], bb = bi[col];
      float m = -INFINITY;
#pragma unroll
      for (int mt = 0; mt < 2; ++mt)
#pragma unroll
        for (int r = 0; r < 4; ++r) m = fmaxf(m, lrelu(acc[mt][nt][r] * s + bb));
      m = fmaxf(m, __shfl_xor(m, 16, 64));
      m = fmaxf(m, __shfl_xor(m, 32, 64));
      if (fq == 0) Red[wv][nt * 16 + fm] = m;
    }
    __syncthreads();
    if (tid < 64) {
      float m = fmaxf(fmaxf(Red[0][tid], Red[1][tid]), fmaxf(Red[2][tid], Red[3][tid]));
      atomicMax(&gmax[bidx * Ncols + n0 + tid], okey(m));
    }
  }
}

// ---------------- MFMA bf16 EdgeConv (layer 4): 320 edges x 64 cols / block ----------------
__global__ __launch_bounds__(256) void k_edgem(
    const __hip_bfloat16* __restrict__ F, int ldf, int coff, int K,
    const __hip_bfloat16* __restrict__ Wl,  // [N][K] bf16
    const float* __restrict__ sc, const float* __restrict__ bi,
    const float* __restrict__ T, int N,
    const int* __restrict__ idx,
    float* __restrict__ outf, __hip_bfloat16* __restrict__ outb) {
  __shared__ __align__(16) char smem[320 * 66 * 2];  // 42240 B, overlaid stage/Ys
  __hip_bfloat16* Al = (__hip_bfloat16*)smem;              // 320*40
  __hip_bfloat16* Bl = (__hip_bfloat16*)(smem + 25600);    // 64*40
  __hip_bfloat16* Ys = (__hip_bfloat16*)smem;              // 320*66 (post-loop)
  const int tid = threadIdx.x, lane = tid & 63, wv = tid >> 6;
  const int blk = blockIdx.x, n0 = blockIdx.y * 64;
  const int arow = tid >> 2, akc = (tid & 3) * 8;
  const int fm = lane & 15, fq = lane >> 4;
  const __hip_bfloat16* ap[5];
#pragma unroll
  for (int l = 0; l < 5; ++l) {
    int row = arow + l * 64;
    int e = blk * 320 + row;
    int p = e / 20;
    int j = idx[(size_t)p * 20 + (e - p * 20)];
    int src = ((p >> 12) << 12) + j;
    ap[l] = F + (size_t)src * ldf + coff + akc;
  }
  f32x4 acc[5][4];
#pragma unroll
  for (int l = 0; l < 5; ++l)
#pragma unroll
    for (int nt = 0; nt < 4; ++nt) acc[l][nt] = (f32x4){0.f, 0.f, 0.f, 0.f};
  for (int c0 = 0; c0 < K; c0 += 32) {
#pragma unroll
    for (int l = 0; l < 5; ++l)
      *(float4*)&Al[(arow + l * 64) * 40 + akc] = *(const float4*)(ap[l] + c0);
    *(float4*)&Bl[arow * 40 + akc] = *(const float4*)(Wl + (size_t)(n0 + arow) * K + c0 + akc);
    __syncthreads();
    bf16x8 af[5], bfr[4];
#pragma unroll
    for (int l = 0; l < 5; ++l)
      af[l] = *(const bf16x8*)&Al[(wv * 80 + l * 16 + fm) * 40 + fq * 8];
#pragma unroll
    for (int nt = 0; nt < 4; ++nt)
      bfr[nt] = *(const bf16x8*)&Bl[(nt * 16 + fm) * 40 + fq * 8];
#pragma unroll
    for (int l = 0; l < 5; ++l)
#pragma unroll
      for (int nt = 0; nt < 4; ++nt)
        acc[l][nt] = __builtin_amdgcn_mfma_f32_16x16x32_bf16(af[l], bfr[nt], acc[l][nt], 0, 0, 0);
    __syncthreads();
  }
#pragma unroll
  for (int l = 0; l < 5; ++l)
#pragma unroll
    for (int nt = 0; nt < 4; ++nt)
#pragma unroll
      for (int r = 0; r < 4; ++r)
        Ys[(wv * 80 + l * 16 + fq * 4 + r) * 66 + nt * 16 + fm] = __float2bfloat16(acc[l][nt][r]);
  __syncthreads();
  const int col = tid & 63;
#pragma unroll
  for (int gi = 0; gi < 4; ++gi) {
    int grp = wv + gi * 4;
    float m = -INFINITY;
#pragma unroll
    for (int k = 0; k < 20; ++k)
      m = fmaxf(m, __bfloat162float(Ys[(grp * 20 + k) * 66 + col]));
    int p = blk * 16 + grp;
    int o = n0 + col;
    float v = lrelu((m + T[(size_t)p * N + o]) * sc[o] + bi[o]);
    outf[(size_t)p * 512 + o] = v;
    outb[(size_t)p * 512 + o] = __float2bfloat16(v);
  }
}

// ---------------- bias2: one wave per (b,o) ----------------
__global__ __launch_bounds__(256) void k_bias2(const unsigned* __restrict__ gk,
                                               const float* __restrict__ Ws1,
                                               float* __restrict__ b2g) {
  const int lane = threadIdx.x & 63;
  const int wid = (blockIdx.x * 256 + threadIdx.x) >> 6;  // 0..1023
  const int b = wid >> 9, o = wid & 511;
  const float* wr = Ws1 + (size_t)o * 1536 + 512;
  const unsigned* g = gk + b * 1024;
  float acc = 0.f;
#pragma unroll
  for (int c = lane; c < 1024; c += 64) acc = fmaf(dekey(g[c]), wr[c], acc);
#pragma unroll
  for (int off = 32; off; off >>= 1) acc += __shfl_xor(acc, off, 64);
  if (lane == 0) b2g[b * 512 + o] = acc;
}

// ---------------- final head: out = H(8192x256) . Ws3^T + bs3 (fp32) ----------------
__global__ __launch_bounds__(256) void k_out(const float* __restrict__ H,
                                             const float* __restrict__ Ws3,
                                             const float* __restrict__ bs3,
                                             float* __restrict__ out) {
  __shared__ float Ws[13][256];
  const int tid = threadIdx.x;
  for (int e = tid; e < 13 * 256; e += 256) Ws[e >> 8][e & 255] = Ws3[e];
  __syncthreads();
  const int rloc = tid >> 4, o = tid & 15;
  const int row = blockIdx.x * 16 + rloc;
  if (o < 13) {
    const float* h = H + (size_t)row * 256;
    float acc = 0.f;
    for (int c = 0; c < 256; ++c) acc = fmaf(h[c], Ws[o][c], acc);
    out[(size_t)row * 13 + o] = acc + bs3[o];
  }
}

extern "C" void kernel_launch(void* const* d_in, const int* in_sizes, int n_in,
                              void* d_out, int out_size, void* d_ws, size_t ws_size,
                              hipStream_t stream) {
  const float* X   = (const float*)d_in[0];
  const float* W1  = (const float*)d_in[1];
  const float* S1  = (const float*)d_in[2];
  const float* B1  = (const float*)d_in[3];
  const float* W2  = (const float*)d_in[4];
  const float* S2  = (const float*)d_in[5];
  const float* B2  = (const float*)d_in[6];
  const float* W3  = (const float*)d_in[7];
  const float* S3  = (const float*)d_in[8];
  const float* B3  = (const float*)d_in[9];
  const float* W4  = (const float*)d_in[10];
  const float* S4  = (const float*)d_in[11];
  const float* B4  = (const float*)d_in[12];
  const float* Wg  = (const float*)d_in[13];
  const float* Sg  = (const float*)d_in[14];
  const float* Bg  = (const float*)d_in[15];
  const float* Ws1 = (const float*)d_in[16];
  const float* Ss1 = (const float*)d_in[17];
  const float* Bs1 = (const float*)d_in[18];
  const float* Ws2 = (const float*)d_in[19];
  const float* Ss2 = (const float*)d_in[20];
  const float* Bs2 = (const float*)d_in[21];
  const float* Ws3 = (const float*)d_in[22];
  const float* Bs3 = (const float*)d_in[23];

  char* ws = (char*)d_ws;
  float*           xxb   = (float*)(ws + 0);            // 32 KB
  int*             idxb  = (int*)(ws + 32768);          // 640 KB
  unsigned*        gk    = (unsigned*)(ws + 688128);    // 8 KB
  float*           b2g   = (float*)(ws + 696320);       // 4 KB
  __hip_bfloat16*  Wgb   = (__hip_bfloat16*)(ws + 1048576);  // 1 MB
  __hip_bfloat16*  Ws1b  = (__hip_bfloat16*)(ws + 2097152);  // 512 KB
  __hip_bfloat16*  Ws2b  = (__hip_bfloat16*)(ws + 2621440);  // 256 KB
  __hip_bfloat16*  Wlb4  = (__hip_bfloat16*)(ws + 2883584);  // 64 KB
  __hip_bfloat16*  Wdb4  = (__hip_bfloat16*)(ws + 2949120);  // 64 KB
  __hip_bfloat16*  xcatb = (__hip_bfloat16*)(ws + 3145728);  // 8 MB
  float*           xcat  = (float*)(ws + 11534336);          // 16 MB
  char*            region = ws + 28311552;                   // dist16 / Tbuf+h1b
  unsigned short*  dist16 = (unsigned short*)(region);       // 64 MB (kNN only)
  float*           Tbuf  = (float*)(region);                 // 8 MB (post-kNN)
  __hip_bfloat16*  h1b   = (__hip_bfloat16*)(region + 8388608);

  hipMemsetAsync(gk, 0, 2 * 1024 * sizeof(unsigned), stream);

  // weight bf16 packs (L4 + head only; L1-L3 weights stay fp32)
  k_conv<<<dim3(256, 2), dim3(64), 0, stream>>>(W4, 256, 0, 0, 128, Wlb4);
  k_conv<<<dim3(256, 2), dim3(64), 0, stream>>>(W4, 256, 128, 1, 128, Wdb4);
  k_conv<<<dim3(1024, 8), dim3(64), 0, stream>>>(Wg, 512, 0, 0, 512, Wgb);
  k_conv<<<dim3(512, 8), dim3(64), 0, stream>>>(Ws1, 1536, 0, 0, 512, Ws1b);
  k_conv<<<dim3(256, 8), dim3(64), 0, stream>>>(Ws2, 512, 0, 0, 512, Ws2b);

  // kNN passes 2-4: u16 dist matrix + rank-by-count top-20
  auto run_knn = [&](const float* F, int ldf, int C) {
    k_xx<<<dim3(2048), dim3(256), 0, stream>>>(F, ldf, C, xxb);
    k_dist<<<dim3(2080, 1, 2), dim3(256), 0, stream>>>(F, ldf, C, xxb, dist16);
    k_topk16<<<dim3(1024, 2), dim3(256), 0, stream>>>(dist16, F, ldf, C, xxb, idxb);
  };

  // ---- Layer 1 (C=3 -> 64, fp32 exact): fused kNN, no dist matrix ----
  k_xx<<<dim3(2048), dim3(256), 0, stream>>>(X, 3, 3, xxb);
  k_knn3<<<dim3(2048), dim3(256), 0, stream>>>(X, xxb, idxb);
  k_edge1<<<dim3(2048), dim3(256), 0, stream>>>(X, W1, S1, B1, idxb, xcat, xcatb);

  // ---- Layer 2 (64 -> 64), fp32 (feeds kNN — must stay exact) ----
  run_knn(xcat, 512, 64);
  k_pwT<<<dim3(128, 1), dim3(256), 0, stream>>>(xcat, 512, 64, W2, 128, 64, Tbuf, 64);
  k_edge<<<dim3(2048, 1), dim3(256), 0, stream>>>(xcat, 512, 64, W2, S2, B2,
      idxb, Tbuf, 64, xcat + 64, xcatb + 64);

  // ---- Layer 3 (64 -> 128), fp32 (feeds kNN) ----
  run_knn(xcat + 64, 512, 64);
  k_pwT<<<dim3(128, 2), dim3(256), 0, stream>>>(xcat + 64, 512, 64, W3, 128, 64, Tbuf, 128);
  k_edge<<<dim3(2048, 2), dim3(256), 0, stream>>>(xcat + 64, 512, 64, W3, S3, B3,
      idxb, Tbuf, 128, xcat + 128, xcatb + 128);

  // ---- Layer 4 (128 -> 256), bf16 MFMA (x4 feeds nothing discrete) ----
  run_knn(xcat + 128, 512, 128);
  k_mm<0><<<dim3(64, 4), dim3(256), 0, stream>>>(xcatb + 128, 512, 128, Wdb4,
      nullptr, nullptr, nullptr, 256, Tbuf, 256, nullptr, 0, nullptr);
  k_edgem<<<dim3(512, 4), dim3(256), 0, stream>>>(xcatb, 512, 128, 128, Wlb4,
      S4, B4, Tbuf, 256, idxb, xcat + 256, xcatb + 256);

  // ---- head (all bf16 MFMA) ----
  k_mm<2><<<dim3(64, 16), dim3(256), 0, stream>>>(xcatb, 512, 512, Wgb,
      Sg, Bg, nullptr, 1024, nullptr, 0, nullptr, 0, gk);
  k_bias2<<<dim3(256), dim3(256), 0, stream>>>(gk, Ws1, b2g);
  k_mm<1><<<dim3(64, 8), dim3(256), 0, stream>>>(xcatb, 512, 512, Ws1b,
      Ss1, Bs1, b2g, 512, nullptr, 0, h1b, 512, nullptr);
  k_mm<1><<<dim3(64, 4), dim3(256), 0, stream>>>(h1b, 512, 512, Ws2b,
      Ss2, Bs2, nullptr, 256, Tbuf, 256, nullptr, 0, nullptr);
  k_out<<<dim3(512), dim3(256), 0, stream>>>(Tbuf, Ws3, Bs3, (float*)d_out);
}

// Round 15
// 611.000 us; speedup vs baseline: 1.2199x; 1.2199x over previous
//
#include <hip/hip_runtime.h>
#include <hip/hip_bf16.h>

// DGCNN_Seg forward. B=2, N=4096, K=20. fp32 in/out.
// Round 30: R29 minus one bug. Fused k_knn3 was 196us: lane-contiguous
// chunks (j=lane*64+t) made every load instruction touch 64 cache lines
// (768B lane stride), ~4 loads/key streamed 2.2x -> issue-bound at 16%
// VALU. Transpose ownership to j=t*64+lane: wave reads 768B contiguous
// per t (~12 lines, 5x fewer transactions). Selection is mapping-
// independent (packs carry global j; rank-by-count orders globally).
// Everything else = R29 (k_dist 64x64 @80us, rank topk16 @37us, verified).

#define DEVI static __device__ __forceinline__
typedef __attribute__((ext_vector_type(8))) short bf16x8;   // 8 bf16 = 4 VGPR
typedef __attribute__((ext_vector_type(4))) float f32x4;    // MFMA acc
typedef unsigned long long ull;

DEVI float lrelu(float y) { return y > 0.f ? y : 0.2f * y; }
DEVI unsigned okey(float f) {
  unsigned u = __float_as_uint(f);
  return (f < 0.f) ? ~u : (u | 0x80000000u);
}
DEVI float dekey(unsigned k) {
  return __uint_as_float((k & 0x80000000u) ? (k & 0x7fffffffu) : ~k);
}

// ---------------- weight fp32 -> bf16 pack ----------------
__global__ __launch_bounds__(64) void k_conv(const float* __restrict__ src, int lds, int off,
                                             int sub, int Kc, __hip_bfloat16* __restrict__ dst) {
  int o = blockIdx.x, c = blockIdx.y * 64 + threadIdx.x;
  float v = src[(size_t)o * lds + off + c];
  if (sub) v -= src[(size_t)o * lds + c];
  dst[(size_t)o * Kc + c] = __float2bfloat16(v);
}

// ---------------- row squared-norms: one wave per row ----------------
__global__ __launch_bounds__(256) void k_xx(const float* __restrict__ F, int ldf, int C,
                                            float* __restrict__ xx) {
  int lane = threadIdx.x & 63;
  int row = blockIdx.x * 4 + (threadIdx.x >> 6);
  const float* f = F + (size_t)row * ldf;
  float s = 0.f;
  for (int c = lane; c < C; c += 64) { float v = f[c]; s += v * v; }
#pragma unroll
  for (int off = 32; off; off >>= 1) s += __shfl_xor(s, off, 64);
  if (lane == 0) xx[row] = s;
}

// ---------------- fused kNN pass 1 (C=3): one wave/row, rank-by-count ----------------
// Keys streamed on the fly, lane owns j = t*64+lane (coalesced: at each t
// the wave reads 64 consecutive float3s). Phase A: lane-min -> LDS u64
// rank-by-count -> (hk,hj) = 20th smallest lane-min (superset bound).
// Phase B: re-stream predicate -> prefix-compact (key,j) pairs to LDS ->
// u64 rank-by-count -> lanes write op[rank], ascending (key,j) == jax.
__global__ __launch_bounds__(256) void k_knn3(const float* __restrict__ xf,
                                              const float* __restrict__ xx,
                                              int* __restrict__ idx) {
  __shared__ ull LP[4][64];   // phase-A lane-min packs
  __shared__ ull LQ[4][64];   // candidate (key<<32|j) pairs
  const int tid = threadIdx.x, lane = tid & 63, wv = tid >> 6;
  const int row = blockIdx.x * 4 + wv;  // 0..8191
  const int b = row >> 12, i = row & 4095;
  const float* xb = xf + (size_t)(b << 12) * 3;
  const float* xxb = xx + (b << 12);
  const float xi0 = xb[(size_t)i * 3], xi1 = xb[(size_t)i * 3 + 1], xi2 = xb[(size_t)i * 3 + 2];
  const float xxi = xxb[i];
  int* op = idx + (size_t)row * 20;
  auto key1 = [&](int t) {
    const int j = t * 64 + lane;
    const float y0 = xb[(size_t)j * 3], y1 = xb[(size_t)j * 3 + 1], y2 = xb[(size_t)j * 3 + 2];
    // R21-verified chain: dot = fmaf(xi2,y2, fmaf(xi1,y1, xi0*y0))
    const float dot = fmaf(xi2, y2, fmaf(xi1, y1, xi0 * y0));
    return okey(xxi + xxb[j] - 2.f * dot);
  };
  // ---- phase A: lane-min (strict < keeps smallest t -> smallest j) ----
  unsigned mk = 0xFFFFFFFFu;
  int mp = 0;
#pragma unroll 8
  for (int t = 0; t < 64; ++t) {
    unsigned k = key1(t);
    if (k < mk) { mk = k; mp = t; }
  }
  const ull mine = ((ull)mk << 32) | (unsigned)(mp * 64 + lane);
  LP[wv][lane] = mine;
  asm volatile("s_waitcnt lgkmcnt(0)" ::: "memory");
  __builtin_amdgcn_sched_barrier(0);
  int rank = 0;
#pragma unroll
  for (int t = 0; t < 64; ++t) rank += (LP[wv][t] < mine) ? 1 : 0;
  const ull bal = __ballot(rank == 19);
  const int sl = (int)(__ffsll((unsigned long long)bal) - 1);
  const unsigned hk = __shfl((unsigned)(mine >> 32), sl, 64);
  const unsigned hj = __shfl((unsigned)(mine & 0xFFFFFFFFu), sl, 64);
  // ---- phase B: predicate re-stream + count ----
  ull pmask = 0;
  int cnt = 0;
#pragma unroll 8
  for (int t = 0; t < 64; ++t) {
    unsigned k = key1(t);
    unsigned j = (unsigned)(t * 64 + lane);
    if (k < hk || (k == hk && j <= hj)) { pmask |= 1ull << t; ++cnt; }
  }
  int inc = cnt;
#pragma unroll
  for (int off = 1; off < 64; off <<= 1) {
    int v = __shfl_up(inc, off, 64);
    if (lane >= off) inc += v;
  }
  const int total = __shfl(inc, 63, 64);
  if (total <= 64) {
    LQ[wv][lane] = 0xFFFFFFFFFFFFFFFFull;
    asm volatile("s_waitcnt lgkmcnt(0)" ::: "memory");
    __builtin_amdgcn_sched_barrier(0);
    int s = inc - cnt;
    while (pmask) {
      int t = (int)(__ffsll(pmask) - 1);
      pmask &= pmask - 1;
      LQ[wv][s++] = ((ull)key1(t) << 32) | (unsigned)(t * 64 + lane);
    }
    asm volatile("s_waitcnt lgkmcnt(0)" ::: "memory");
    __builtin_amdgcn_sched_barrier(0);
    const ull me = LQ[wv][lane];
    int r2 = 0;
#pragma unroll
    for (int t = 0; t < 64; ++t) r2 += (LQ[wv][t] < me) ? 1 : 0;
    if (lane < total && r2 < 20) op[r2] = (int)(me & 4095u);
    return;
  }
  // ---- fallback (massive ties; never runs): threshold-walk pop min ----
  ull last = 0;
  for (int r = 0; r < 20; ++r) {
    ull best = 0xFFFFFFFFFFFFFFFFull;
    for (int t = 0; t < 64; ++t) {
      ull p = ((ull)key1(t) << 32) | (unsigned)(t * 64 + lane);
      if (p > last && p < best) best = p;
    }
    unsigned bh = (unsigned)(best >> 32), bl = (unsigned)best;
#pragma unroll
    for (int off = 32; off; off >>= 1) {
      unsigned qh = __shfl_xor(bh, off, 64);
      unsigned ql = __shfl_xor(bl, off, 64);
      if (qh < bh || (qh == bh && ql < bl)) { bh = qh; bl = ql; }
    }
    if (lane == 0) op[r] = (int)(bl & 4095u);
    last = ((ull)bh << 32) | bl;
  }
}

// ---------------- pairwise distances: 64(i)x64(j) tile, 4x4 acc, u16 keys ----------------
// Triangular bj>=bi (2080 tiles/batch); diagonal tiles cover both triangles,
// off-diagonal mirror from registers. Stores okey(d)>>16 (u16). fmaf order
// ascending c (zero-padded tail exact) -> k_topk16 recompute bit-identical.
__global__ __launch_bounds__(256) void k_dist(const float* __restrict__ F, int ldf, int C,
                                              const float* __restrict__ xx,
                                              unsigned short* __restrict__ D) {
  __shared__ __align__(16) float As[16][68];
  __shared__ __align__(16) float Bs[16][68];
  const int tid = threadIdx.x;
  const int tx = tid & 15, ty = tid >> 4;
  int bi, bj;
  {
    int t = blockIdx.x;
    bi = 0;
    while (t >= 64 - bi) { t -= 64 - bi; ++bi; }
    bj = bi + t;
  }
  const int b = blockIdx.z;
  unsigned short* Db = D + (size_t)b * 4096 * 4096;
  const int i0 = bi * 64, j0 = bj * 64;
  const float* Fb = F + (size_t)b * 4096 * ldf;
  const float* xxb = xx + b * 4096;
  const int row = tid >> 2, q = (tid & 3) * 4;  // stage: 64 rows x 16 cols
  float acc[4][4] = {};
  for (int c0 = 0; c0 < C; c0 += 16) {
    if (C - c0 >= 16) {
      float4 a = *(const float4*)(Fb + (size_t)(i0 + row) * ldf + c0 + q);
      As[q + 0][row] = a.x; As[q + 1][row] = a.y; As[q + 2][row] = a.z; As[q + 3][row] = a.w;
      float4 w = *(const float4*)(Fb + (size_t)(j0 + row) * ldf + c0 + q);
      Bs[q + 0][row] = w.x; Bs[q + 1][row] = w.y; Bs[q + 2][row] = w.z; Bs[q + 3][row] = w.w;
    } else {
#pragma unroll
      for (int e = 0; e < 4; ++e) {
        int c = c0 + q + e;
        As[q + e][row] = (c < C) ? Fb[(size_t)(i0 + row) * ldf + c] : 0.f;
        Bs[q + e][row] = (c < C) ? Fb[(size_t)(j0 + row) * ldf + c] : 0.f;
      }
    }
    __syncthreads();
#pragma unroll
    for (int kk = 0; kk < 16; ++kk) {
      const float4 a4 = *(const float4*)&As[kk][ty * 4];
      const float4 b4 = *(const float4*)&Bs[kk][tx * 4];
      const float av[4] = {a4.x, a4.y, a4.z, a4.w};
      const float bv[4] = {b4.x, b4.y, b4.z, b4.w};
#pragma unroll
      for (int ii = 0; ii < 4; ++ii)
#pragma unroll
        for (int jj = 0; jj < 4; ++jj)
          acc[ii][jj] = fmaf(av[ii], bv[jj], acc[ii][jj]);
    }
    __syncthreads();
  }
  // normal store: rows i0+ty*4+ii, cols j0+tx*4.. (uint2 = 4 u16)
#pragma unroll
  for (int ii = 0; ii < 4; ++ii) {
    const int i = i0 + ty * 4 + ii;
    const float xi = xxb[i];
    unsigned k0 = okey(xi + xxb[j0 + tx * 4 + 0] - 2.f * acc[ii][0]) >> 16;
    unsigned k1 = okey(xi + xxb[j0 + tx * 4 + 1] - 2.f * acc[ii][1]) >> 16;
    unsigned k2 = okey(xi + xxb[j0 + tx * 4 + 2] - 2.f * acc[ii][2]) >> 16;
    unsigned k3 = okey(xi + xxb[j0 + tx * 4 + 3] - 2.f * acc[ii][3]) >> 16;
    uint2 o;
    o.x = (k1 << 16) | k0;
    o.y = (k3 << 16) | k2;
    *(uint2*)&Db[(size_t)i * 4096 + j0 + tx * 4] = o;
  }
  // mirror store (strictly off-diagonal tiles): transpose block
  if (bj > bi) {
#pragma unroll
    for (int jj = 0; jj < 4; ++jj) {
      const int j = j0 + tx * 4 + jj;
      const float xj = xxb[j];
      unsigned h0 = okey(xxb[i0 + ty * 4 + 0] + xj - 2.f * acc[0][jj]) >> 16;
      unsigned h1 = okey(xxb[i0 + ty * 4 + 1] + xj - 2.f * acc[1][jj]) >> 16;
      unsigned h2 = okey(xxb[i0 + ty * 4 + 2] + xj - 2.f * acc[2][jj]) >> 16;
      unsigned h3 = okey(xxb[i0 + ty * 4 + 3] + xj - 2.f * acc[3][jj]) >> 16;
      uint2 m;
      m.x = (h1 << 16) | h0;
      m.y = (h3 << 16) | h2;
      *(uint2*)&Db[(size_t)j * 4096 + i0 + ty * 4] = m;
    }
  }
}

// ---------------- top-20 v3: rank-by-count, minimal cross-lane ----------------
__global__ __launch_bounds__(256) void k_topk16(const unsigned short* __restrict__ Dk,
                                                const float* __restrict__ F, int ldf, int C,
                                                const float* __restrict__ xx,
                                                int* __restrict__ idx) {
  __shared__ unsigned LM[4][64];   // lane-min packs
  __shared__ unsigned LC[4][64];   // candidate j list
  __shared__ ull LPair[4][64];     // (ekey<<32)|j pairs
  const int tid = threadIdx.x, lane = tid & 63, wv = tid >> 6;
  const int ir = blockIdx.x * 4 + wv;   // 0..4095
  const int b = blockIdx.y;
  const unsigned short* drow = Dk + (size_t)b * 4096 * 4096 + (size_t)ir * 4096;
  const float* Fb = F + (size_t)b * 4096 * ldf;
  const float* xxb = xx + (size_t)b * 4096;
  int* op = idx + ((size_t)b * 4096 + ir) * 20;
  // load row: 8 x uint4 (8 u16 keys each), j = q*512 + lane*8 + e
  uint4 kw[8];
  {
    const uint4* dp = (const uint4*)drow;
#pragma unroll
    for (int q = 0; q < 8; ++q) kw[q] = dp[q * 64 + lane];
  }
  // pin in VGPRs (R25: compiler rematerialized -> 2x global reads)
#pragma unroll
  for (int q = 0; q < 8; ++q)
    asm volatile("" : "+v"(kw[q].x), "+v"(kw[q].y), "+v"(kw[q].z), "+v"(kw[q].w));
  // ---- phase A: lane-min of packs (k16<<12 | j) ----
  unsigned smin = 0xFFFFFFFFu;
#pragma unroll
  for (int q = 0; q < 8; ++q) {
    const unsigned jb = (unsigned)(q * 512 + lane * 8);
    const unsigned w[4] = {kw[q].x, kw[q].y, kw[q].z, kw[q].w};
#pragma unroll
    for (int h = 0; h < 4; ++h) {
      const unsigned p0 = ((w[h] & 0xFFFFu) << 12) | (jb + 2 * h);
      const unsigned p1 = ((w[h] >> 16) << 12) | (jb + 2 * h + 1);
      smin = p0 < smin ? p0 : smin;
      smin = p1 < smin ? p1 : smin;
    }
  }
  // rank-by-count over 64 lane-mins (LDS broadcast reads, no crossbar)
  LM[wv][lane] = smin;
  asm volatile("s_waitcnt lgkmcnt(0)" ::: "memory");
  __builtin_amdgcn_sched_barrier(0);
  int rank = 0;
#pragma unroll
  for (int t = 0; t < 64; ++t) rank += (LM[wv][t] < smin) ? 1 : 0;
  const ull bal = __ballot(rank == 19);
  const int sl = (int)(__ffsll((unsigned long long)bal) - 1);
  const unsigned t16 = __shfl(smin, sl, 64) >> 12;
  // ---- phase B: candidate mask (k16 <= t16) from regs ----
  ull pmask = 0;
  int cnt = 0;
#pragma unroll
  for (int q = 0; q < 8; ++q) {
    const unsigned w[4] = {kw[q].x, kw[q].y, kw[q].z, kw[q].w};
#pragma unroll
    for (int h = 0; h < 4; ++h) {
      if ((w[h] & 0xFFFFu) <= t16) { pmask |= 1ull << (q * 8 + 2 * h);     ++cnt; }
      if ((w[h] >> 16)     <= t16) { pmask |= 1ull << (q * 8 + 2 * h + 1); ++cnt; }
    }
  }
  int inc = cnt;
#pragma unroll
  for (int off = 1; off < 64; off <<= 1) {
    int v = __shfl_up(inc, off, 64);
    if (lane >= off) inc += v;
  }
  const int total = __shfl(inc, 63, 64);
  if (total <= 64) {
    int s = inc - cnt;
    while (pmask) {
      int t = (int)(__ffsll(pmask) - 1);
      pmask &= pmask - 1;
      LC[wv][s++] = (unsigned)((t >> 3) * 512 + lane * 8 + (t & 7));
    }
    asm volatile("s_waitcnt lgkmcnt(0)" ::: "memory");
    __builtin_amdgcn_sched_barrier(0);
    unsigned cp = (lane < total) ? LC[wv][lane] : 0xFFFFFFFFu;
    asm volatile("s_waitcnt lgkmcnt(0)" ::: "memory");
    unsigned ekey = 0xFFFFFFFFu;
    if (lane < total) {
      const float* xip = Fb + (size_t)ir * ldf;
      const float* xjp = Fb + (size_t)cp * ldf;
      float dot = 0.f;
      int c = 0;
      for (; c + 4 <= C; c += 4) {   // same chain order as k_dist (ascending c)
        const float4 a = *(const float4*)(xip + c);
        const float4 g = *(const float4*)(xjp + c);
        dot = fmaf(a.x, g.x, dot);
        dot = fmaf(a.y, g.y, dot);
        dot = fmaf(a.z, g.z, dot);
        dot = fmaf(a.w, g.w, dot);
      }
      for (; c < C; ++c) dot = fmaf(xip[c], xjp[c], dot);
      ekey = okey(xxb[ir] + xxb[cp] - 2.f * dot);
    }
    // final rank-by-count on (ekey, j) u64 pairs (LDS broadcast)
    const ull me = ((ull)ekey << 32) | cp;
    LPair[wv][lane] = me;
    asm volatile("s_waitcnt lgkmcnt(0)" ::: "memory");
    __builtin_amdgcn_sched_barrier(0);
    int r2 = 0;
#pragma unroll
    for (int t = 0; t < 64; ++t) r2 += (LPair[wv][t] < me) ? 1 : 0;
    if (lane < total && r2 < 20) op[r2] = (int)cp;
    return;
  }
  // ---- fallback (massive u16 ties; correct, effectively never runs) ----
  ull consumed = 0;
  for (int r = 0; r < 20; ++r) {
    unsigned bk = 0xFFFFFFFFu, bp = 0xFFFFu;
    for (int t = 0; t < 64; ++t) {
      if ((consumed >> t) & 1ull) continue;
      unsigned p = (unsigned)(t * 64 + lane);
      const float* xip = Fb + (size_t)ir * ldf;
      const float* xjp = Fb + (size_t)p * ldf;
      float dot = 0.f;
      for (int c = 0; c < C; ++c) dot = fmaf(xip[c], xjp[c], dot);
      unsigned ek = okey(xxb[ir] + xxb[p] - 2.f * dot);
      if (ek < bk || (ek == bk && p < bp)) { bk = ek; bp = p; }
    }
    unsigned mk = bk, mp = bp;
#pragma unroll
    for (int off = 32; off; off >>= 1) {
      unsigned ok2 = __shfl_xor(mk, off, 64);
      unsigned op2 = __shfl_xor(mp, off, 64);
      if (ok2 < mk || (ok2 == mk && op2 < mp)) { mk = ok2; mp = op2; }
    }
    if (lane == 0) op[r] = (int)mp;
    if (bk == mk && bp == mp) consumed |= 1ull << (mp >> 6);
  }
}

// ---------------- EdgeConv layer 1 (fp32, Cin=3): one wave per point ----------------
__global__ __launch_bounds__(256) void k_edge1(const float* __restrict__ xf,
                                               const float* __restrict__ W1,
                                               const float* __restrict__ s1,
                                               const float* __restrict__ b1,
                                               const int* __restrict__ idx,
                                               float* __restrict__ xcat,
                                               __hip_bfloat16* __restrict__ xcatb) {
  const int lane = threadIdx.x & 63;
  const int p = blockIdx.x * 4 + (threadIdx.x >> 6);
  const int bb = p >> 12;
  float wl[3], wr[3];
#pragma unroll
  for (int c = 0; c < 3; ++c) {
    wl[c] = W1[lane * 6 + c];
    wr[c] = W1[lane * 6 + 3 + c];
  }
  const float s = s1[lane], bi = b1[lane];
  const float* xc = xf + (size_t)p * 3;
  const float x0 = xc[0], x1 = xc[1], x2 = xc[2];
  const float t = x0 * (wr[0] - wl[0]) + x1 * (wr[1] - wl[1]) + x2 * (wr[2] - wl[2]);
  const int* ir = idx + (size_t)p * 20;
  float best = -INFINITY;
  for (int k = 0; k < 20; ++k) {
    int j = ir[k];
    const float* xn = xf + ((size_t)(bb << 12) + j) * 3;
    float y = t + xn[0] * wl[0] + xn[1] * wl[1] + xn[2] * wl[2];
    y = lrelu(y * s + bi);
    best = fmaxf(best, y);
  }
  xcat[(size_t)p * 512 + lane] = best;
  xcatb[(size_t)p * 512 + lane] = __float2bfloat16(best);
}

// ---------------- fp32 pointwise GEMM, raw store (T for layers 2-3) ----------------
__global__ __launch_bounds__(256) void k_pwT(const float* __restrict__ A, int lda, int K,
                                             const float* __restrict__ W, int ldw, int wsub,
                                             float* __restrict__ out, int ldo) {
  __shared__ __align__(16) float As[16][68];
  __shared__ __align__(16) float Bs[16][68];
  const int tid = threadIdx.x;
  const int tx = tid & 15, ty = tid >> 4;
  const int i0 = blockIdx.x * 64, o0 = blockIdx.y * 64;
  const int row = tid >> 2, q = (tid & 3) * 4;
  float acc[4][4] = {};
  for (int c0 = 0; c0 < K; c0 += 16) {
    float4 a = *(const float4*)(A + (size_t)(i0 + row) * lda + c0 + q);
    As[q + 0][row] = a.x; As[q + 1][row] = a.y; As[q + 2][row] = a.z; As[q + 3][row] = a.w;
    const float* wp = W + (size_t)(o0 + row) * ldw + c0 + q;
#pragma unroll
    for (int e = 0; e < 4; ++e) Bs[q + e][row] = wp[wsub + e] - wp[e];
    __syncthreads();
#pragma unroll
    for (int kk = 0; kk < 16; ++kk) {
      const float4 a4 = *(const float4*)&As[kk][ty * 4];
      const float4 b4 = *(const float4*)&Bs[kk][tx * 4];
      const float av[4] = {a4.x, a4.y, a4.z, a4.w};
      const float bv[4] = {b4.x, b4.y, b4.z, b4.w};
#pragma unroll
      for (int ii = 0; ii < 4; ++ii)
#pragma unroll
        for (int jj = 0; jj < 4; ++jj)
          acc[ii][jj] = fmaf(av[ii], bv[jj], acc[ii][jj]);
    }
    __syncthreads();
  }
#pragma unroll
  for (int ii = 0; ii < 4; ++ii)
#pragma unroll
    for (int jj = 0; jj < 4; ++jj)
      out[(size_t)(i0 + ty * 4 + ii) * ldo + o0 + tx * 4 + jj] = acc[ii][jj];
}

// ---------------- fp32 EdgeConv GEMM (layers 2-3; feeds kNN, stays exact) ----------------
__global__ __launch_bounds__(256) void k_edge(const float* __restrict__ F, int ldf, int Cin,
                                              const float* __restrict__ W,
                                              const float* __restrict__ sc,
                                              const float* __restrict__ bi,
                                              const int* __restrict__ idx,
                                              const float* __restrict__ T, int ldt,
                                              float* __restrict__ out,
                                              __hip_bfloat16* __restrict__ outb) {
  __shared__ float As[16][81];
  __shared__ __align__(16) float Bs[16][68];
  __shared__ float Ys[80][65];
  const int tid = threadIdx.x;
  const int tx = tid & 15, ty = tid >> 4;
  const int r0 = blockIdx.x * 80;
  const int o0 = blockIdx.y * 64;
  const int ldw = 2 * Cin;
  int grow[5], gcol[5];
#pragma unroll
  for (int l = 0; l < 5; ++l) {
    int e = tid + l * 256;
    int rr = e >> 4;
    gcol[l] = e & 15;
    int gr = r0 + rr;
    int p = gr / 20;
    int j = idx[(size_t)p * 20 + (gr % 20)];
    grow[l] = ((p >> 12) << 12) + j;
  }
  float acc[5][4] = {};
  const int wrow = tid >> 2, wq = (tid & 3) * 4;
  for (int c0 = 0; c0 < Cin; c0 += 16) {
#pragma unroll
    for (int l = 0; l < 5; ++l) {
      int e = tid + l * 256;
      As[gcol[l]][e >> 4] = F[(size_t)grow[l] * ldf + c0 + gcol[l]];
    }
    {
      const float* wp = W + (size_t)(o0 + wrow) * ldw + c0 + wq;
#pragma unroll
      for (int e = 0; e < 4; ++e) Bs[wq + e][wrow] = wp[e];
    }
    __syncthreads();
#pragma unroll
    for (int kk = 0; kk < 16; ++kk) {
      float a[5];
#pragma unroll
      for (int l = 0; l < 5; ++l) a[l] = As[kk][ty + l * 16];
      const float4 b4 = *(const float4*)&Bs[kk][tx * 4];
      const float bv[4] = {b4.x, b4.y, b4.z, b4.w};
#pragma unroll
      for (int l = 0; l < 5; ++l)
#pragma unroll
        for (int jj = 0; jj < 4; ++jj)
          acc[l][jj] = fmaf(a[l], bv[jj], acc[l][jj]);
    }
    __syncthreads();
  }
#pragma unroll
  for (int l = 0; l < 5; ++l) {
    int r = ty + l * 16;
    int p = (r0 + r) / 20;
#pragma unroll
    for (int jj = 0; jj < 4; ++jj) {
      int o = o0 + tx * 4 + jj;
      float y = (acc[l][jj] + T[(size_t)p * ldt + o]) * sc[o] + bi[o];
      Ys[r][tx * 4 + jj] = lrelu(y);
    }
  }
  __syncthreads();
  const int grp = tid >> 6, col = tid & 63;
  float m = -INFINITY;
#pragma unroll
  for (int k = 0; k < 20; ++k) m = fmaxf(m, Ys[grp * 20 + k][col]);
  const int p = blockIdx.x * 4 + grp;
  out[(size_t)p * 512 + o0 + col] = m;
  outb[(size_t)p * 512 + o0 + col] = __float2bfloat16(m);
}

// ---------------- MFMA bf16 GEMM: block 128(M)x64(N), 4 waves x (32x64) ----------------
template <int EPI>
__global__ __launch_bounds__(256) void k_mm(
    const __hip_bfloat16* __restrict__ A, int lda, int K,
    const __hip_bfloat16* __restrict__ B,  // [N][K] bf16
    const float* __restrict__ sc, const float* __restrict__ bi,
    const float* __restrict__ extra, int Ncols,
    float* __restrict__ outf, int ldof,
    __hip_bfloat16* __restrict__ outb, int ldob,
    unsigned* __restrict__ gmax) {
  __shared__ __align__(16) __hip_bfloat16 Al[128 * 40];
  __shared__ __align__(16) __hip_bfloat16 Bl[64 * 40];
  __shared__ float Red[4][64];
  const int tid = threadIdx.x, lane = tid & 63, wv = tid >> 6;
  const int m0 = blockIdx.x * 128, n0 = blockIdx.y * 64;
  const int arow = tid >> 2, akc = (tid & 3) * 8;
  const int fm = lane & 15, fq = lane >> 4;
  f32x4 acc[2][4];
#pragma unroll
  for (int mt = 0; mt < 2; ++mt)
#pragma unroll
    for (int nt = 0; nt < 4; ++nt) acc[mt][nt] = (f32x4){0.f, 0.f, 0.f, 0.f};
  for (int c0 = 0; c0 < K; c0 += 32) {
#pragma unroll
    for (int l = 0; l < 2; ++l) {
      int r = arow + l * 64;
      *(float4*)&Al[r * 40 + akc] = *(const float4*)(A + (size_t)(m0 + r) * lda + c0 + akc);
    }
    *(float4*)&Bl[arow * 40 + akc] = *(const float4*)(B + (size_t)(n0 + arow) * K + c0 + akc);
    __syncthreads();
    bf16x8 af[2], bfr[4];
#pragma unroll
    for (int mt = 0; mt < 2; ++mt)
      af[mt] = *(const bf16x8*)&Al[(wv * 32 + mt * 16 + fm) * 40 + fq * 8];
#pragma unroll
    for (int nt = 0; nt < 4; ++nt)
      bfr[nt] = *(const bf16x8*)&Bl[(nt * 16 + fm) * 40 + fq * 8];
#pragma unroll
    for (int mt = 0; mt < 2; ++mt)
#pragma unroll
      for (int nt = 0; nt < 4; ++nt)
        acc[mt][nt] = __builtin_amdgcn_mfma_f32_16x16x32_bf16(af[mt], bfr[nt], acc[mt][nt], 0, 0, 0);
    __syncthreads();
  }
  const int bidx = m0 >> 12;
  if (EPI == 0) {
#pragma unroll
    for (int mt = 0; mt < 2; ++mt)
#pragma unroll
      for (int nt = 0; nt < 4; ++nt)
#pragma unroll
        for (int r = 0; r < 4; ++r)
          outf[(size_t)(m0 + wv * 32 + mt * 16 + fq * 4 + r) * ldof + n0 + nt * 16 + fm] =
              acc[mt][nt][r];
  } else if (EPI == 1) {
#pragma unroll
    for (int nt = 0; nt < 4; ++nt) {
      int col = n0 + nt * 16 + fm;
      float s = sc[col], bb = bi[col];
      float ex = extra ? extra[bidx * Ncols + col] : 0.f;
#pragma unroll
      for (int mt = 0; mt < 2; ++mt)
#pragma unroll
        for (int r = 0; r < 4; ++r) {
          float v = lrelu((acc[mt][nt][r] + ex) * s + bb);
          size_t rr = (size_t)(m0 + wv * 32 + mt * 16 + fq * 4 + r);
          if (outf) outf[rr * ldof + col] = v;
          if (outb) outb[rr * ldob + col] = __float2bfloat16(v);
        }
    }
  } else {
#pragma unroll
    for (int nt = 0; nt < 4; ++nt) {
      int col = n0 + nt * 16 + fm;
      float s = sc[col], bb = bi[col];
      float m = -INFINITY;
#pragma unroll
      for (int mt = 0; mt < 2; ++mt)
#pragma unroll
        for (int r = 0; r < 4; ++r) m = fmaxf(m, lrelu(acc[mt][nt][r] * s + bb));
      m = fmaxf(m, __shfl_xor(m, 16, 64));
      m = fmaxf(m, __shfl_xor(m, 32, 64));
      if (fq == 0) Red[wv][nt * 16 + fm] = m;
    }
    __syncthreads();
    if (tid < 64) {
      float m = fmaxf(fmaxf(Red[0][tid], Red[1][tid]), fmaxf(Red[2][tid], Red[3][tid]));
      atomicMax(&gmax[bidx * Ncols + n0 + tid], okey(m));
    }
  }
}

// ---------------- MFMA bf16 EdgeConv (layer 4): 320 edges x 64 cols / block ----------------
__global__ __launch_bounds__(256) void k_edgem(
    const __hip_bfloat16* __restrict__ F, int ldf, int coff, int K,
    const __hip_bfloat16* __restrict__ Wl,  // [N][K] bf16
    const float* __restrict__ sc, const float* __restrict__ bi,
    const float* __restrict__ T, int N,
    const int* __restrict__ idx,
    float* __restrict__ outf, __hip_bfloat16* __restrict__ outb) {
  __shared__ __align__(16) char smem[320 * 66 * 2];  // 42240 B, overlaid stage/Ys
  __hip_bfloat16* Al = (__hip_bfloat16*)smem;              // 320*40
  __hip_bfloat16* Bl = (__hip_bfloat16*)(smem + 25600);    // 64*40
  __hip_bfloat16* Ys = (__hip_bfloat16*)smem;              // 320*66 (post-loop)
  const int tid = threadIdx.x, lane = tid & 63, wv = tid >> 6;
  const int blk = blockIdx.x, n0 = blockIdx.y * 64;
  const int arow = tid >> 2, akc = (tid & 3) * 8;
  const int fm = lane & 15, fq = lane >> 4;
  const __hip_bfloat16* ap[5];
#pragma unroll
  for (int l = 0; l < 5; ++l) {
    int row = arow + l * 64;
    int e = blk * 320 + row;
    int p = e / 20;
    int j = idx[(size_t)p * 20 + (e - p * 20)];
    int src = ((p >> 12) << 12) + j;
    ap[l] = F + (size_t)src * ldf + coff + akc;
  }
  f32x4 acc[5][4];
#pragma unroll
  for (int l = 0; l < 5; ++l)
#pragma unroll
    for (int nt = 0; nt < 4; ++nt) acc[l][nt] = (f32x4){0.f, 0.f, 0.f, 0.f};
  for (int c0 = 0; c0 < K; c0 += 32) {
#pragma unroll
    for (int l = 0; l < 5; ++l)
      *(float4*)&Al[(arow + l * 64) * 40 + akc] = *(const float4*)(ap[l] + c0);
    *(float4*)&Bl[arow * 40 + akc] = *(const float4*)(Wl + (size_t)(n0 + arow) * K + c0 + akc);
    __syncthreads();
    bf16x8 af[5], bfr[4];
#pragma unroll
    for (int l = 0; l < 5; ++l)
      af[l] = *(const bf16x8*)&Al[(wv * 80 + l * 16 + fm) * 40 + fq * 8];
#pragma unroll
    for (int nt = 0; nt < 4; ++nt)
      bfr[nt] = *(const bf16x8*)&Bl[(nt * 16 + fm) * 40 + fq * 8];
#pragma unroll
    for (int l = 0; l < 5; ++l)
#pragma unroll
      for (int nt = 0; nt < 4; ++nt)
        acc[l][nt] = __builtin_amdgcn_mfma_f32_16x16x32_bf16(af[l], bfr[nt], acc[l][nt], 0, 0, 0);
    __syncthreads();
  }
#pragma unroll
  for (int l = 0; l < 5; ++l)
#pragma unroll
    for (int nt = 0; nt < 4; ++nt)
#pragma unroll
      for (int r = 0; r < 4; ++r)
        Ys[(wv * 80 + l * 16 + fq * 4 + r) * 66 + nt * 16 + fm] = __float2bfloat16(acc[l][nt][r]);
  __syncthreads();
  const int col = tid & 63;
#pragma unroll
  for (int gi = 0; gi < 4; ++gi) {
    int grp = wv + gi * 4;
    float m = -INFINITY;
#pragma unroll
    for (int k = 0; k < 20; ++k)
      m = fmaxf(m, __bfloat162float(Ys[(grp * 20 + k) * 66 + col]));
    int p = blk * 16 + grp;
    int o = n0 + col;
    float v = lrelu((m + T[(size_t)p * N + o]) * sc[o] + bi[o]);
    outf[(size_t)p * 512 + o] = v;
    outb[(size_t)p * 512 + o] = __float2bfloat16(v);
  }
}

// ---------------- bias2: one wave per (b,o) ----------------
__global__ __launch_bounds__(256) void k_bias2(const unsigned* __restrict__ gk,
                                               const float* __restrict__ Ws1,
                                               float* __restrict__ b2g) {
  const int lane = threadIdx.x & 63;
  const int wid = (blockIdx.x * 256 + threadIdx.x) >> 6;  // 0..1023
  const int b = wid >> 9, o = wid & 511;
  const float* wr = Ws1 + (size_t)o * 1536 + 512;
  const unsigned* g = gk + b * 1024;
  float acc = 0.f;
#pragma unroll
  for (int c = lane; c < 1024; c += 64) acc = fmaf(dekey(g[c]), wr[c], acc);
#pragma unroll
  for (int off = 32; off; off >>= 1) acc += __shfl_xor(acc, off, 64);
  if (lane == 0) b2g[b * 512 + o] = acc;
}

// ---------------- final head: out = H(8192x256) . Ws3^T + bs3 (fp32) ----------------
__global__ __launch_bounds__(256) void k_out(const float* __restrict__ H,
                                             const float* __restrict__ Ws3,
                                             const float* __restrict__ bs3,
                                             float* __restrict__ out) {
  __shared__ float Ws[13][256];
  const int tid = threadIdx.x;
  for (int e = tid; e < 13 * 256; e += 256) Ws[e >> 8][e & 255] = Ws3[e];
  __syncthreads();
  const int rloc = tid >> 4, o = tid & 15;
  const int row = blockIdx.x * 16 + rloc;
  if (o < 13) {
    const float* h = H + (size_t)row * 256;
    float acc = 0.f;
    for (int c = 0; c < 256; ++c) acc = fmaf(h[c], Ws[o][c], acc);
    out[(size_t)row * 13 + o] = acc + bs3[o];
  }
}

extern "C" void kernel_launch(void* const* d_in, const int* in_sizes, int n_in,
                              void* d_out, int out_size, void* d_ws, size_t ws_size,
                              hipStream_t stream) {
  const float* X   = (const float*)d_in[0];
  const float* W1  = (const float*)d_in[1];
  const float* S1  = (const float*)d_in[2];
  const float* B1  = (const float*)d_in[3];
  const float* W2  = (const float*)d_in[4];
  const float* S2  = (const float*)d_in[5];
  const float* B2  = (const float*)d_in[6];
  const float* W3  = (const float*)d_in[7];
  const float* S3  = (const float*)d_in[8];
  const float* B3  = (const float*)d_in[9];
  const float* W4  = (const float*)d_in[10];
  const float* S4  = (const float*)d_in[11];
  const float* B4  = (const float*)d_in[12];
  const float* Wg  = (const float*)d_in[13];
  const float* Sg  = (const float*)d_in[14];
  const float* Bg  = (const float*)d_in[15];
  const float* Ws1 = (const float*)d_in[16];
  const float* Ss1 = (const float*)d_in[17];
  const float* Bs1 = (const float*)d_in[18];
  const float* Ws2 = (const float*)d_in[19];
  const float* Ss2 = (const float*)d_in[20];
  const float* Bs2 = (const float*)d_in[21];
  const float* Ws3 = (const float*)d_in[22];
  const float* Bs3 = (const float*)d_in[23];

  char* ws = (char*)d_ws;
  float*           xxb   = (float*)(ws + 0);            // 32 KB
  int*             idxb  = (int*)(ws + 32768);          // 640 KB
  unsigned*        gk    = (unsigned*)(ws + 688128);    // 8 KB
  float*           b2g   = (float*)(ws + 696320);       // 4 KB
  __hip_bfloat16*  Wgb   = (__hip_bfloat16*)(ws + 1048576);  // 1 MB
  __hip_bfloat16*  Ws1b  = (__hip_bfloat16*)(ws + 2097152);  // 512 KB
  __hip_bfloat16*  Ws2b  = (__hip_bfloat16*)(ws + 2621440);  // 256 KB
  __hip_bfloat16*  Wlb4  = (__hip_bfloat16*)(ws + 2883584);  // 64 KB
  __hip_bfloat16*  Wdb4  = (__hip_bfloat16*)(ws + 2949120);  // 64 KB
  __hip_bfloat16*  xcatb = (__hip_bfloat16*)(ws + 3145728);  // 8 MB
  float*           xcat  = (float*)(ws + 11534336);          // 16 MB
  char*            region = ws + 28311552;                   // dist16 / Tbuf+h1b
  unsigned short*  dist16 = (unsigned short*)(region);       // 64 MB (kNN only)
  float*           Tbuf  = (float*)(region);                 // 8 MB (post-kNN)
  __hip_bfloat16*  h1b   = (__hip_bfloat16*)(region + 8388608);

  hipMemsetAsync(gk, 0, 2 * 1024 * sizeof(unsigned), stream);

  // weight bf16 packs (L4 + head only; L1-L3 weights stay fp32)
  k_conv<<<dim3(256, 2), dim3(64), 0, stream>>>(W4, 256, 0, 0, 128, Wlb4);
  k_conv<<<dim3(256, 2), dim3(64), 0, stream>>>(W4, 256, 128, 1, 128, Wdb4);
  k_conv<<<dim3(1024, 8), dim3(64), 0, stream>>>(Wg, 512, 0, 0, 512, Wgb);
  k_conv<<<dim3(512, 8), dim3(64), 0, stream>>>(Ws1, 1536, 0, 0, 512, Ws1b);
  k_conv<<<dim3(256, 8), dim3(64), 0, stream>>>(Ws2, 512, 0, 0, 512, Ws2b);

  // kNN passes 2-4: u16 dist matrix + rank-by-count top-20
  auto run_knn = [&](const float* F, int ldf, int C) {
    k_xx<<<dim3(2048), dim3(256), 0, stream>>>(F, ldf, C, xxb);
    k_dist<<<dim3(2080, 1, 2), dim3(256), 0, stream>>>(F, ldf, C, xxb, dist16);
    k_topk16<<<dim3(1024, 2), dim3(256), 0, stream>>>(dist16, F, ldf, C, xxb, idxb);
  };

  // ---- Layer 1 (C=3 -> 64, fp32 exact): fused kNN, no dist matrix ----
  k_xx<<<dim3(2048), dim3(256), 0, stream>>>(X, 3, 3, xxb);
  k_knn3<<<dim3(2048), dim3(256), 0, stream>>>(X, xxb, idxb);
  k_edge1<<<dim3(2048), dim3(256), 0, stream>>>(X, W1, S1, B1, idxb, xcat, xcatb);

  // ---- Layer 2 (64 -> 64), fp32 (feeds kNN — must stay exact) ----
  run_knn(xcat, 512, 64);
  k_pwT<<<dim3(128, 1), dim3(256), 0, stream>>>(xcat, 512, 64, W2, 128, 64, Tbuf, 64);
  k_edge<<<dim3(2048, 1), dim3(256), 0, stream>>>(xcat, 512, 64, W2, S2, B2,
      idxb, Tbuf, 64, xcat + 64, xcatb + 64);

  // ---- Layer 3 (64 -> 128), fp32 (feeds kNN) ----
  run_knn(xcat + 64, 512, 64);
  k_pwT<<<dim3(128, 2), dim3(256), 0, stream>>>(xcat + 64, 512, 64, W3, 128, 64, Tbuf, 128);
  k_edge<<<dim3(2048, 2), dim3(256), 0, stream>>>(xcat + 64, 512, 64, W3, S3, B3,
      idxb, Tbuf, 128, xcat + 128, xcatb + 128);

  // ---- Layer 4 (128 -> 256), bf16 MFMA (x4 feeds nothing discrete) ----
  run_knn(xcat + 128, 512, 128);
  k_mm<0><<<dim3(64, 4), dim3(256), 0, stream>>>(xcatb + 128, 512, 128, Wdb4,
      nullptr, nullptr, nullptr, 256, Tbuf, 256, nullptr, 0, nullptr);
  k_edgem<<<dim3(512, 4), dim3(256), 0, stream>>>(xcatb, 512, 128, 128, Wlb4,
      S4, B4, Tbuf, 256, idxb, xcat + 256, xcatb + 256);

  // ---- head (all bf16 MFMA) ----
  k_mm<2><<<dim3(64, 16), dim3(256), 0, stream>>>(xcatb, 512, 512, Wgb,
      Sg, Bg, nullptr, 1024, nullptr, 0, nullptr, 0, gk);
  k_bias2<<<dim3(256), dim3(256), 0, stream>>>(gk, Ws1, b2g);
  k_mm<1><<<dim3(64, 8), dim3(256), 0, stream>>>(xcatb, 512, 512, Ws1b,
      Ss1, Bs1, b2g, 512, nullptr, 0, h1b, 512, nullptr);
  k_mm<1><<<dim3(64, 4), dim3(256), 0, stream>>>(h1b, 512, 512, Ws2b,
      Ss2, Bs2, nullptr, 256, Tbuf, 256, nullptr, 0, nullptr);
  k_out<<<dim3(512), dim3(256), 0, stream>>>(Tbuf, Ws3, Bs3, (float*)d_out);
}